// Round 8
// baseline (1540.674 us; speedup 1.0000x reference)
//
#include <hip/hip_runtime.h>

#define NN 50000
#define NE 1600000
#define NR 8
#define ND 128
#define NL 3
#define RN (NR * NN)
#define SCAN_BLK 1024
#define NB ((RN + SCAN_BLK - 1) / SCAN_BLK)  // 391
#define LN_EPS 1e-5f
#define PADF 132   // f32 elems per LDS acc/epilogue row (132%4==0, stride-2 atomics 2-way)
#define PADB 136   // bf16 elems per root-staging row
#define PADB2 68   // dwords per root-staging row

typedef __attribute__((ext_vector_type(8))) short short8;
typedef __attribute__((ext_vector_type(4))) float float4v;

__device__ __forceinline__ float bflo(unsigned u) { return __uint_as_float(u << 16); }
__device__ __forceinline__ float bfhi(unsigned u) { return __uint_as_float(u & 0xFFFF0000u); }
__device__ __forceinline__ unsigned f2bf(float f) {
    unsigned u = __float_as_uint(f);
    return (u + 0x7FFFu + ((u >> 16) & 1u)) >> 16;   // RNE
}
__device__ __forceinline__ unsigned pack2(float lo, float hi) {
    return f2bf(lo) | (f2bf(hi) << 16);
}

// h (row-major bf16x2): h[n*64+dw] = emb[x[n]] cols 2dw,2dw+1
__global__ __launch_bounds__(256) void k_gather(const int* __restrict__ x,
                                                const float* __restrict__ emb,
                                                unsigned* __restrict__ h) {
    int i = blockIdx.x * 256 + threadIdx.x;
    if (i >= NN * 64) return;
    int n = i >> 6, dw = i & 63;
    float2 v = *(const float2*)&emb[(size_t)x[n] * ND + 2 * dw];
    h[i] = pack2(v.x, v.y);
}

// weights -> bf16 B-fragment layout: wb[m][((kk*8+ft)*64+lane)*8+j] = W_m[kk*32+(lane>>4)*8+j][ft*16+(lane&15)]
__global__ __launch_bounds__(256) void k_wprep(const float* __restrict__ w_rel,
                                               const float* __restrict__ w_root,
                                               unsigned short* __restrict__ wb) {
    int i = blockIdx.x * 256 + threadIdx.x;
    if (i >= 27 * 16384) return;
    int m = i >> 14;
    int idx = i & 16383;
    int j = idx & 7;
    int lane = (idx >> 3) & 63;
    int ft = (idx >> 9) & 7;
    int kk = idx >> 12;
    int row = kk * 32 + (lane >> 4) * 8 + j;
    int col = ft * 16 + (lane & 15);
    const float* W = (m < 24) ? (w_rel + (size_t)m * 16384)
                              : (w_root + (size_t)(m - 24) * 16384);
    wb[i] = (unsigned short)f2bf(W[row * ND + col]);
}

__global__ __launch_bounds__(256) void k_count(const int* __restrict__ dst,
                                               const int* __restrict__ et,
                                               int* __restrict__ cnt) {
    int e = blockIdx.x * 256 + threadIdx.x;
    if (e >= NE) return;
    atomicAdd(&cnt[et[e] * NN + dst[e]], 1);
}

// scan over cnt -> rowstart (exclusive); also emits inv = 1/max(cnt,1)
__global__ __launch_bounds__(256) void k_scan1(const int* __restrict__ cnt,
                                               int* __restrict__ rowstart,
                                               int* __restrict__ bsum,
                                               float* __restrict__ inv) {
    __shared__ int tmp[256];
    int t = threadIdx.x;
    int base = blockIdx.x * SCAN_BLK + t * 4;
    int v[4];
#pragma unroll
    for (int i = 0; i < 4; i++) v[i] = (base + i < RN) ? cnt[base + i] : 0;
    int local = v[0] + v[1] + v[2] + v[3];
    tmp[t] = local;
    __syncthreads();
    for (int off = 1; off < 256; off <<= 1) {
        int x = (t >= off) ? tmp[t - off] : 0;
        __syncthreads();
        tmp[t] += x;
        __syncthreads();
    }
    int run = tmp[t] - local;
    if (t == 255) bsum[blockIdx.x] = tmp[t];
#pragma unroll
    for (int i = 0; i < 4; i++) {
        if (base + i < RN) {
            rowstart[base + i] = run;
            inv[base + i] = 1.0f / (float)(v[i] > 1 ? v[i] : 1);
        }
        run += v[i];
    }
}

__global__ __launch_bounds__(256) void k_scan2(const int* __restrict__ bsum,
                                               int* __restrict__ boff) {
    __shared__ int tmp[256];
    int t = threadIdx.x;
    int v0 = (2 * t < NB) ? bsum[2 * t] : 0;
    int v1 = (2 * t + 1 < NB) ? bsum[2 * t + 1] : 0;
    int local = v0 + v1;
    tmp[t] = local;
    __syncthreads();
    for (int off = 1; off < 256; off <<= 1) {
        int x = (t >= off) ? tmp[t - off] : 0;
        __syncthreads();
        tmp[t] += x;
        __syncthreads();
    }
    int excl = tmp[t] - local;
    if (2 * t < NB) boff[2 * t] = excl;
    if (2 * t + 1 < NB) boff[2 * t + 1] = excl + v0;
}

__global__ __launch_bounds__(256) void k_scan3(int* __restrict__ rowstart,
                                               const int* __restrict__ boff) {
    int i = blockIdx.x * 256 + threadIdx.x;
    if (i < RN) rowstart[i] += boff[i >> 10];
    if (i == 0) rowstart[RN] = NE;
}

// fill packed adj: low16 = src, high16 = dst (both < 65536)
__global__ __launch_bounds__(256) void k_fill(const int* __restrict__ src,
                                              const int* __restrict__ dst,
                                              const int* __restrict__ et,
                                              const int* __restrict__ rowstart,
                                              int* __restrict__ cnt,
                                              unsigned* __restrict__ adjp) {
    int e = blockIdx.x * 256 + threadIdx.x;
    if (e >= NE) return;
    int d = dst[e];
    int seg = et[e] * NN + d;
    int c = atomicSub(&cnt[seg], 1);
    adjp[rowstart[seg] + c - 1] = (unsigned)src[e] | ((unsigned)d << 16);
}

// Fused RGCN layer, edge-parallel gather.
// Block = 64 dst rows, 8 waves. Per relation: the block's edges are the
// CONTIGUOUS adj range [rowstart[r*NN+n0], rowstart[r*NN+n0+64]). Each wave
// streams a contiguous chunk, whole-wave-per-edge (64 lanes = 256B row),
// 4-edge groups + 1-group lookahead (8 loads in flight), run-combining in
// registers, fp32 LDS atomics on collisions. No dependent chains, no per-row
// imbalance. Mean scale + bf16 cvt folded into MFMA A-frag read.
__global__ __launch_bounds__(512) void k_layer(const unsigned* __restrict__ h32,
                                               const unsigned* __restrict__ adjp,
                                               const int* __restrict__ rowstart,
                                               const float* __restrict__ inv,
                                               const unsigned short* __restrict__ wrel,
                                               const unsigned short* __restrict__ wroot,
                                               const float* __restrict__ bias,
                                               const float* __restrict__ gamma,
                                               const float* __restrict__ beta,
                                               float* __restrict__ out_f,
                                               unsigned* __restrict__ out_h,
                                               int add_res, int last) {
    __shared__ float SLF[64 * PADF];                 // 33792 B: fp32 acc / root bf16 / epilogue
    unsigned short* SLB = (unsigned short*)SLF;
    unsigned* SLB32 = (unsigned*)SLF;

    int tid = threadIdx.x;
    int wave = tid >> 6, lane = tid & 63;
    int quad = lane >> 4, l15 = lane & 15;
    int n0 = blockIdx.x * 64;
    int nend = (n0 + 64 < NN) ? (n0 + 64) : NN;

    float4v acc[8];
#pragma unroll
    for (int i = 0; i < 8; i++) acc[i] = (float4v){0.f, 0.f, 0.f, 0.f};

    for (int r = 0; r < NR; r++) {
        // zero fp32 acc tile
        for (int i = tid; i < 64 * PADF; i += 512) SLF[i] = 0.f;
        __syncthreads();

        int e0 = rowstart[r * NN + n0];
        int e1 = rowstart[r * NN + nend];
        int len = e1 - e0;
        if (len > 0) {
            int per = ((len + 31) >> 5) << 2;        // edges/wave, multiple of 4
            int cs = e0 + wave * per;
            int ce = cs + per; if (ce > e1) ce = e1;
            if (cs < ce) {
                int clampE = e1 - 1;
                float f0 = 0.f, f1 = 0.f;
                int currow = -1;
                unsigned pk[4], uu[4];
#pragma unroll
                for (int i = 0; i < 4; i++) {
                    int ei = cs + i; ei = ei <= clampE ? ei : clampE;
                    pk[i] = adjp[ei];
                }
#pragma unroll
                for (int i = 0; i < 4; i++)
                    uu[i] = h32[(size_t)(pk[i] & 0xFFFFu) * 64 + lane];
                for (int e = cs; e < ce; e += 4) {
                    unsigned npk[4], nuu[4];
#pragma unroll
                    for (int i = 0; i < 4; i++) { npk[i] = pk[i]; nuu[i] = uu[i]; }
                    int en = e + 4;
                    if (en < ce) {
#pragma unroll
                        for (int i = 0; i < 4; i++) {
                            int ei = en + i; ei = ei <= clampE ? ei : clampE;
                            npk[i] = adjp[ei];
                        }
#pragma unroll
                        for (int i = 0; i < 4; i++)
                            nuu[i] = h32[(size_t)(npk[i] & 0xFFFFu) * 64 + lane];
                    }
#pragma unroll
                    for (int i = 0; i < 4; i++) {
                        if (e + i < ce) {                    // wave-uniform
                            int row = (int)(pk[i] >> 16) - n0;
                            if (row != currow) {             // wave-uniform
                                if (currow >= 0) {
                                    atomicAdd(&SLF[currow * PADF + 2 * lane], f0);
                                    atomicAdd(&SLF[currow * PADF + 2 * lane + 1], f1);
                                }
                                currow = row; f0 = 0.f; f1 = 0.f;
                            }
                            f0 += bflo(uu[i]); f1 += bfhi(uu[i]);
                        }
                    }
#pragma unroll
                    for (int i = 0; i < 4; i++) { pk[i] = npk[i]; uu[i] = nuu[i]; }
                }
                if (currow >= 0) {
                    atomicAdd(&SLF[currow * PADF + 2 * lane], f0);
                    atomicAdd(&SLF[currow * PADF + 2 * lane + 1], f1);
                }
            }
        }
        __syncthreads();

        if (wave < 4) {
            int g = n0 + wave * 16 + l15;
            int gi = g < NN ? g : NN - 1;
            float sc = inv[r * NN + gi];
            const unsigned short* WB = wrel + r * 16384;
            const float* rowp = &SLF[(wave * 16 + l15) * PADF];
#pragma unroll
            for (int kk = 0; kk < 4; kk++) {
                float4 x0 = *(const float4*)&rowp[kk * 32 + quad * 8];
                float4 x1 = *(const float4*)&rowp[kk * 32 + quad * 8 + 4];
                short8 af;
                af[0] = (short)f2bf(x0.x * sc);
                af[1] = (short)f2bf(x0.y * sc);
                af[2] = (short)f2bf(x0.z * sc);
                af[3] = (short)f2bf(x0.w * sc);
                af[4] = (short)f2bf(x1.x * sc);
                af[5] = (short)f2bf(x1.y * sc);
                af[6] = (short)f2bf(x1.z * sc);
                af[7] = (short)f2bf(x1.w * sc);
#pragma unroll
                for (int ft = 0; ft < 8; ft++) {
                    short8 bf = *(const short8*)&WB[((kk * 8 + ft) * 64 + lane) * 8];
                    acc[ft] = __builtin_amdgcn_mfma_f32_16x16x32_bf16(af, bf, acc[ft], 0, 0, 0);
                }
            }
        }
        __syncthreads();
    }

    // root transform: stage bf16 h tile (coalesced), MFMA with wroot
    for (int i = tid; i < 64 * 64; i += 512) {
        int row = i >> 6, dw = i & 63;
        int g = n0 + row;
        SLB32[row * PADB2 + dw] = (g < NN) ? h32[(size_t)g * 64 + dw] : 0u;
    }
    __syncthreads();
    if (wave < 4) {
#pragma unroll
        for (int kk = 0; kk < 4; kk++) {
            short8 af = *(const short8*)&SLB[(wave * 16 + l15) * PADB + kk * 32 + quad * 8];
#pragma unroll
            for (int ft = 0; ft < 8; ft++) {
                short8 bf = *(const short8*)&wroot[((kk * 8 + ft) * 64 + lane) * 8];
                acc[ft] = __builtin_amdgcn_mfma_f32_16x16x32_bf16(af, bf, acc[ft], 0, 0, 0);
            }
        }
    }
    __syncthreads();

    // epilogue: acc (C layout: row=quad*4+rg, col=ft*16+l15) -> fp32 LDS (waves 0-3)
    if (wave < 4) {
#pragma unroll
        for (int ft = 0; ft < 8; ft++)
#pragma unroll
            for (int rg = 0; rg < 4; rg++)
                SLF[(wave * 16 + quad * 4 + rg) * PADF + ft * 16 + l15] = acc[ft][rg];
    }
    __syncthreads();

    float2 bia = *(const float2*)&bias[2 * lane];
    float2 gam = *(const float2*)&gamma[2 * lane];
    float2 bet = *(const float2*)&beta[2 * lane];

    for (int i = 0; i < 8; i++) {
        int row = wave * 8 + i;
        int g = n0 + row;
        if (g >= NN) continue;                       // wave-uniform
        float v0 = SLF[row * PADF + 2 * lane] + bia.x;
        float v1 = SLF[row * PADF + 2 * lane + 1] + bia.y;
        float s = v0 + v1;
#pragma unroll
        for (int off = 32; off > 0; off >>= 1) s += __shfl_xor(s, off, 64);
        float mu = s * (1.0f / ND);
        float e0 = v0 - mu, e1 = v1 - mu;
        float vs = e0 * e0 + e1 * e1;
#pragma unroll
        for (int off = 32; off > 0; off >>= 1) vs += __shfl_xor(vs, off, 64);
        float rr = rsqrtf(vs * (1.0f / ND) + LN_EPS);
        float o0 = fmaxf(e0 * rr * gam.x + bet.x, 0.0f);
        float o1 = fmaxf(e1 * rr * gam.y + bet.y, 0.0f);
        if (add_res) {
            unsigned u = h32[(size_t)g * 64 + lane];
            o0 += bflo(u);
            o1 += bfhi(u);
        }
        if (last) {
            *(float2*)&out_f[(size_t)g * ND + 2 * lane] = make_float2(o0, o1);
        } else {
            out_h[(size_t)g * 64 + lane] = pack2(o0, o1);
        }
    }
}

extern "C" void kernel_launch(void* const* d_in, const int* in_sizes, int n_in,
                              void* d_out, int out_size, void* d_ws, size_t ws_size,
                              hipStream_t stream) {
    const int*   x      = (const int*)d_in[0];
    const int*   ei     = (const int*)d_in[1];
    const int*   et     = (const int*)d_in[2];
    const float* emb    = (const float*)d_in[3];
    const float* w_rel  = (const float*)d_in[4];
    const float* w_root = (const float*)d_in[5];
    const float* bias   = (const float*)d_in[6];
    const float* gamma  = (const float*)d_in[7];
    const float* beta   = (const float*)d_in[8];
    float* out = (float*)d_out;

    char* ws = (char*)d_ws;
    unsigned* h_a      = (unsigned*)(ws);                    // 12.8 MB (bf16x2, row-major)
    unsigned* h_b      = (unsigned*)(ws + 12800000);         // 12.8 MB
    int*      cnt      = (int*)     (ws + 25600000);         // 1.6 MB
    float*    inv      = (float*)   (ws + 27200000);         // 1.6 MB
    int*      rowstart = (int*)     (ws + 28800000);         // 1.6 MB + 4
    int*      bsum     = (int*)     (ws + 30400064);
    int*      boff     = (int*)     (ws + 30402048);
    unsigned* adjp     = (unsigned*)(ws + 30404096);         // 6.4 MB
    unsigned short* wb = (unsigned short*)(ws + 36804096);   // 884736 B

    const int* src = ei;
    const int* dst = ei + NE;

    hipMemsetAsync(cnt, 0, RN * sizeof(int), stream);
    k_gather<<<(NN * 64 + 255) / 256, 256, 0, stream>>>(x, emb, h_a);
    k_wprep<<<(27 * 16384 + 255) / 256, 256, 0, stream>>>(w_rel, w_root, wb);
    k_count<<<(NE + 255) / 256, 256, 0, stream>>>(dst, et, cnt);
    k_scan1<<<NB, 256, 0, stream>>>(cnt, rowstart, bsum, inv);
    k_scan2<<<1, 256, 0, stream>>>(bsum, boff);
    k_scan3<<<(RN + 255) / 256, 256, 0, stream>>>(rowstart, boff);
    k_fill<<<(NE + 255) / 256, 256, 0, stream>>>(src, dst, et, rowstart, cnt, adjp);

    unsigned* h_cur = h_a;
    unsigned* h_nxt = h_b;
    for (int l = 0; l < NL; l++) {
        k_layer<<<(NN + 63) / 64, 512, 0, stream>>>(
            h_cur, adjp, rowstart, inv,
            wb + (size_t)l * 8 * 16384, wb + (size_t)(24 + l) * 16384,
            bias + l * ND, gamma + l * ND, beta + l * ND,
            out, h_nxt, l > 0, l == NL - 1);
        unsigned* t = h_cur; h_cur = h_nxt; h_nxt = t;
    }
}

// Round 9
// 1288.017 us; speedup vs baseline: 1.1962x; 1.1962x over previous
//
#include <hip/hip_runtime.h>

#define NN 50000
#define NE 1600000
#define NR 8
#define ND 128
#define NL 3
#define RN (NR * NN)
#define SCAN_BLK 1024
#define NB ((RN + SCAN_BLK - 1) / SCAN_BLK)  // 391
#define LN_EPS 1e-5f
#define TILE 32
#define PADB 136   // bf16 elems per LDS tile row (row stride 272 B)
#define PADF 132   // f32 elems per epilogue scratch row

typedef __attribute__((ext_vector_type(8))) short short8;
typedef __attribute__((ext_vector_type(4))) float float4v;

__device__ __forceinline__ float bflo(unsigned u) { return __uint_as_float(u << 16); }
__device__ __forceinline__ float bfhi(unsigned u) { return __uint_as_float(u & 0xFFFF0000u); }
__device__ __forceinline__ unsigned f2bf(float f) {
    unsigned u = __float_as_uint(f);
    return (u + 0x7FFFu + ((u >> 16) & 1u)) >> 16;   // RNE
}
__device__ __forceinline__ unsigned pack2(float lo, float hi) {
    return f2bf(lo) | (f2bf(hi) << 16);
}

// h (row-major bf16x2): h[n*64+dw] = emb[x[n]] cols 2dw,2dw+1
__global__ __launch_bounds__(256) void k_gather(const int* __restrict__ x,
                                                const float* __restrict__ emb,
                                                unsigned* __restrict__ h) {
    int i = blockIdx.x * 256 + threadIdx.x;
    if (i >= NN * 64) return;
    int n = i >> 6, dw = i & 63;
    float2 v = *(const float2*)&emb[(size_t)x[n] * ND + 2 * dw];
    h[i] = pack2(v.x, v.y);
}

// weights -> bf16 B-fragment layout: wb[m][((kk*8+ft)*64+lane)*8+j] = W_m[kk*32+(lane>>4)*8+j][ft*16+(lane&15)]
__global__ __launch_bounds__(256) void k_wprep(const float* __restrict__ w_rel,
                                               const float* __restrict__ w_root,
                                               unsigned short* __restrict__ wb) {
    int i = blockIdx.x * 256 + threadIdx.x;
    if (i >= 27 * 16384) return;
    int m = i >> 14;
    int idx = i & 16383;
    int j = idx & 7;
    int lane = (idx >> 3) & 63;
    int ft = (idx >> 9) & 7;
    int kk = idx >> 12;
    int row = kk * 32 + (lane >> 4) * 8 + j;
    int col = ft * 16 + (lane & 15);
    const float* W = (m < 24) ? (w_rel + (size_t)m * 16384)
                              : (w_root + (size_t)(m - 24) * 16384);
    wb[i] = (unsigned short)f2bf(W[row * ND + col]);
}

__global__ __launch_bounds__(256) void k_count(const int* __restrict__ dst,
                                               const int* __restrict__ et,
                                               int* __restrict__ cnt) {
    int e = blockIdx.x * 256 + threadIdx.x;
    if (e >= NE) return;
    atomicAdd(&cnt[et[e] * NN + dst[e]], 1);
}

// scan over cnt -> rowstart (exclusive); also emits inv = 1/max(cnt,1)
__global__ __launch_bounds__(256) void k_scan1(const int* __restrict__ cnt,
                                               int* __restrict__ rowstart,
                                               int* __restrict__ bsum,
                                               float* __restrict__ inv) {
    __shared__ int tmp[256];
    int t = threadIdx.x;
    int base = blockIdx.x * SCAN_BLK + t * 4;
    int v[4];
#pragma unroll
    for (int i = 0; i < 4; i++) v[i] = (base + i < RN) ? cnt[base + i] : 0;
    int local = v[0] + v[1] + v[2] + v[3];
    tmp[t] = local;
    __syncthreads();
    for (int off = 1; off < 256; off <<= 1) {
        int x = (t >= off) ? tmp[t - off] : 0;
        __syncthreads();
        tmp[t] += x;
        __syncthreads();
    }
    int run = tmp[t] - local;
    if (t == 255) bsum[blockIdx.x] = tmp[t];
#pragma unroll
    for (int i = 0; i < 4; i++) {
        if (base + i < RN) {
            rowstart[base + i] = run;
            inv[base + i] = 1.0f / (float)(v[i] > 1 ? v[i] : 1);
        }
        run += v[i];
    }
}

__global__ __launch_bounds__(256) void k_scan2(const int* __restrict__ bsum,
                                               int* __restrict__ boff) {
    __shared__ int tmp[256];
    int t = threadIdx.x;
    int v0 = (2 * t < NB) ? bsum[2 * t] : 0;
    int v1 = (2 * t + 1 < NB) ? bsum[2 * t + 1] : 0;
    int local = v0 + v1;
    tmp[t] = local;
    __syncthreads();
    for (int off = 1; off < 256; off <<= 1) {
        int x = (t >= off) ? tmp[t - off] : 0;
        __syncthreads();
        tmp[t] += x;
        __syncthreads();
    }
    int excl = tmp[t] - local;
    if (2 * t < NB) boff[2 * t] = excl;
    if (2 * t + 1 < NB) boff[2 * t + 1] = excl + v0;
}

__global__ __launch_bounds__(256) void k_scan3(int* __restrict__ rowstart,
                                               const int* __restrict__ boff) {
    int i = blockIdx.x * 256 + threadIdx.x;
    if (i < RN) rowstart[i] += boff[i >> 10];
    if (i == 0) rowstart[RN] = NE;
}

__global__ __launch_bounds__(256) void k_fill(const int* __restrict__ src,
                                              const int* __restrict__ dst,
                                              const int* __restrict__ et,
                                              const int* __restrict__ rowstart,
                                              int* __restrict__ cnt,
                                              int* __restrict__ adj) {
    int e = blockIdx.x * 256 + threadIdx.x;
    if (e >= NE) return;
    int seg = et[e] * NN + dst[e];
    int c = atomicSub(&cnt[seg], 1);
    adj[rowstart[seg] + c - 1] = src[e];
}

// Fused RGCN layer. Block = 32 nodes, 4 waves (256 threads), grid 1563 for
// residency. Gather: 16-lane quad groups, one row per quad (4 concurrent CSR
// chains/wave, 2 batches -> 32 rows). MFMA: waves 0-1 own the two 16-row
// m-tiles (full acc[8] each). Same internals as the verified R6 kernel.
__global__ __launch_bounds__(256) void k_layer(const unsigned* __restrict__ h32,
                                               const int* __restrict__ adj,
                                               const int* __restrict__ rowstart,
                                               const float* __restrict__ inv,
                                               const unsigned short* __restrict__ wrel,
                                               const unsigned short* __restrict__ wroot,
                                               const float* __restrict__ bias,
                                               const float* __restrict__ gamma,
                                               const float* __restrict__ beta,
                                               float* __restrict__ out_f,
                                               unsigned* __restrict__ out_h,
                                               int add_res, int last) {
    __shared__ float SLF[TILE * PADF];               // 16896 B fp32 epilogue scratch
    unsigned short* SLB = (unsigned short*)SLF;      // aliased bf16 tile [32][PADB]
    unsigned* SLB32 = (unsigned*)SLF;

    int tid = threadIdx.x;
    int wave = tid >> 6, lane = tid & 63;
    int quad = lane >> 4, l15 = lane & 15;
    int n0 = blockIdx.x * TILE;

    float4v acc[8];
#pragma unroll
    for (int i = 0; i < 8; i++) acc[i] = (float4v){0.f, 0.f, 0.f, 0.f};

    for (int r = 0; r < NR; r++) {
        // gather+mean: 2 batches of 4 concurrent rows per wave (4 waves x 8 rows)
        for (int b = 0; b < 2; b++) {
            int row = wave * 8 + b * 4 + quad;
            int g = n0 + row;
            float a0 = 0.f, a1 = 0.f, a2 = 0.f, a3 = 0.f,
                  a4 = 0.f, a5 = 0.f, a6 = 0.f, a7 = 0.f;
            if (g < NN) {
                int seg = r * NN + g;
                int st = rowstart[seg], en = rowstart[seg + 1];
                st = st < 0 ? 0 : st;
                en = en > NE ? NE : en;
                float c0 = 0.f, c1 = 0.f, c2 = 0.f, c3 = 0.f,
                      c4 = 0.f, c5 = 0.f, c6 = 0.f, c7 = 0.f;
                int p = st;
                for (; p + 1 < en; p += 2) {
                    unsigned s0 = (unsigned)adj[p], s1 = (unsigned)adj[p + 1];
                    s0 = s0 < NN ? s0 : NN - 1;
                    s1 = s1 < NN ? s1 : NN - 1;
                    uint4 u0 = *(const uint4*)&h32[(size_t)s0 * 64 + l15 * 4];
                    uint4 u1 = *(const uint4*)&h32[(size_t)s1 * 64 + l15 * 4];
                    a0 += bflo(u0.x); a1 += bfhi(u0.x);
                    a2 += bflo(u0.y); a3 += bfhi(u0.y);
                    a4 += bflo(u0.z); a5 += bfhi(u0.z);
                    a6 += bflo(u0.w); a7 += bfhi(u0.w);
                    c0 += bflo(u1.x); c1 += bfhi(u1.x);
                    c2 += bflo(u1.y); c3 += bfhi(u1.y);
                    c4 += bflo(u1.z); c5 += bfhi(u1.z);
                    c6 += bflo(u1.w); c7 += bfhi(u1.w);
                }
                if (p < en) {
                    unsigned s0 = (unsigned)adj[p];
                    s0 = s0 < NN ? s0 : NN - 1;
                    uint4 u0 = *(const uint4*)&h32[(size_t)s0 * 64 + l15 * 4];
                    a0 += bflo(u0.x); a1 += bfhi(u0.x);
                    a2 += bflo(u0.y); a3 += bfhi(u0.y);
                    a4 += bflo(u0.z); a5 += bfhi(u0.z);
                    a6 += bflo(u0.w); a7 += bfhi(u0.w);
                }
                float sc = inv[seg];
                a0 = (a0 + c0) * sc; a1 = (a1 + c1) * sc;
                a2 = (a2 + c2) * sc; a3 = (a3 + c3) * sc;
                a4 = (a4 + c4) * sc; a5 = (a5 + c5) * sc;
                a6 = (a6 + c6) * sc; a7 = (a7 + c7) * sc;
            }
            uint4 w;
            w.x = pack2(a0, a1); w.y = pack2(a2, a3);
            w.z = pack2(a4, a5); w.w = pack2(a6, a7);
            *(uint4*)&SLB32[row * (PADB / 2) + l15 * 4] = w;
        }
        __syncthreads();
        if (wave < 2) {
            const unsigned short* WB = wrel + r * 16384;
#pragma unroll
            for (int kk = 0; kk < 4; kk++) {
                short8 af = *(const short8*)&SLB[(wave * 16 + l15) * PADB + kk * 32 + quad * 8];
#pragma unroll
                for (int ft = 0; ft < 8; ft++) {
                    short8 bf = *(const short8*)&WB[((kk * 8 + ft) * 64 + lane) * 8];
                    acc[ft] = __builtin_amdgcn_mfma_f32_16x16x32_bf16(af, bf, acc[ft], 0, 0, 0);
                }
            }
        }
        __syncthreads();
    }

    // root transform: stage h tile (coalesced) then MFMA
#pragma unroll
    for (int i = 0; i < 8; i++) {
        int idx = tid + i * 256;                     // 2048 dwords
        int row = idx >> 6, dw = idx & 63;
        int g = n0 + row;
        SLB32[row * (PADB / 2) + dw] = (g < NN) ? h32[(size_t)g * 64 + dw] : 0u;
    }
    __syncthreads();
    if (wave < 2) {
#pragma unroll
        for (int kk = 0; kk < 4; kk++) {
            short8 af = *(const short8*)&SLB[(wave * 16 + l15) * PADB + kk * 32 + quad * 8];
#pragma unroll
            for (int ft = 0; ft < 8; ft++) {
                short8 bf = *(const short8*)&wroot[((kk * 8 + ft) * 64 + lane) * 8];
                acc[ft] = __builtin_amdgcn_mfma_f32_16x16x32_bf16(af, bf, acc[ft], 0, 0, 0);
            }
        }
    }
    __syncthreads();

    // epilogue: acc (C layout: row=quad*4+reg, col=ft*16+l15) -> fp32 LDS (waves 0-1)
    if (wave < 2) {
#pragma unroll
        for (int ft = 0; ft < 8; ft++)
#pragma unroll
            for (int rg = 0; rg < 4; rg++)
                SLF[(wave * 16 + quad * 4 + rg) * PADF + ft * 16 + l15] = acc[ft][rg];
    }
    __syncthreads();

    float2 bia = *(const float2*)&bias[2 * lane];
    float2 gam = *(const float2*)&gamma[2 * lane];
    float2 bet = *(const float2*)&beta[2 * lane];

    for (int i = 0; i < 8; i++) {
        int row = wave * 8 + i;
        int g = n0 + row;
        if (g >= NN) continue;                       // wave-uniform
        float v0 = SLF[row * PADF + 2 * lane] + bia.x;
        float v1 = SLF[row * PADF + 2 * lane + 1] + bia.y;
        float s = v0 + v1;
#pragma unroll
        for (int off = 32; off > 0; off >>= 1) s += __shfl_xor(s, off, 64);
        float mu = s * (1.0f / ND);
        float e0 = v0 - mu, e1 = v1 - mu;
        float vs = e0 * e0 + e1 * e1;
#pragma unroll
        for (int off = 32; off > 0; off >>= 1) vs += __shfl_xor(vs, off, 64);
        float rr = rsqrtf(vs * (1.0f / ND) + LN_EPS);
        float o0 = fmaxf(e0 * rr * gam.x + bet.x, 0.0f);
        float o1 = fmaxf(e1 * rr * gam.y + bet.y, 0.0f);
        if (add_res) {
            unsigned u = h32[(size_t)g * 64 + lane];
            o0 += bflo(u);
            o1 += bfhi(u);
        }
        if (last) {
            *(float2*)&out_f[(size_t)g * ND + 2 * lane] = make_float2(o0, o1);
        } else {
            out_h[(size_t)g * 64 + lane] = pack2(o0, o1);
        }
    }
}

extern "C" void kernel_launch(void* const* d_in, const int* in_sizes, int n_in,
                              void* d_out, int out_size, void* d_ws, size_t ws_size,
                              hipStream_t stream) {
    const int*   x      = (const int*)d_in[0];
    const int*   ei     = (const int*)d_in[1];
    const int*   et     = (const int*)d_in[2];
    const float* emb    = (const float*)d_in[3];
    const float* w_rel  = (const float*)d_in[4];
    const float* w_root = (const float*)d_in[5];
    const float* bias   = (const float*)d_in[6];
    const float* gamma  = (const float*)d_in[7];
    const float* beta   = (const float*)d_in[8];
    float* out = (float*)d_out;

    char* ws = (char*)d_ws;
    unsigned* h_a      = (unsigned*)(ws);                    // 12.8 MB (bf16x2, row-major)
    unsigned* h_b      = (unsigned*)(ws + 12800000);         // 12.8 MB
    int*      cnt      = (int*)     (ws + 25600000);         // 1.6 MB
    float*    inv      = (float*)   (ws + 27200000);         // 1.6 MB
    int*      rowstart = (int*)     (ws + 28800000);         // 1.6 MB + 4
    int*      bsum     = (int*)     (ws + 30400064);
    int*      boff     = (int*)     (ws + 30402048);
    int*      adj      = (int*)     (ws + 30404096);         // 6.4 MB
    unsigned short* wb = (unsigned short*)(ws + 36804096);   // 884736 B

    const int* src = ei;
    const int* dst = ei + NE;

    hipMemsetAsync(cnt, 0, RN * sizeof(int), stream);
    k_gather<<<(NN * 64 + 255) / 256, 256, 0, stream>>>(x, emb, h_a);
    k_wprep<<<(27 * 16384 + 255) / 256, 256, 0, stream>>>(w_rel, w_root, wb);
    k_count<<<(NE + 255) / 256, 256, 0, stream>>>(dst, et, cnt);
    k_scan1<<<NB, 256, 0, stream>>>(cnt, rowstart, bsum, inv);
    k_scan2<<<1, 256, 0, stream>>>(bsum, boff);
    k_scan3<<<(RN + 255) / 256, 256, 0, stream>>>(rowstart, boff);
    k_fill<<<(NE + 255) / 256, 256, 0, stream>>>(src, dst, et, rowstart, cnt, adj);

    unsigned* h_cur = h_a;
    unsigned* h_nxt = h_b;
    for (int l = 0; l < NL; l++) {
        k_layer<<<(NN + TILE - 1) / TILE, 256, 0, stream>>>(
            h_cur, adj, rowstart, inv,
            wb + (size_t)l * 8 * 16384, wb + (size_t)(24 + l) * 16384,
            bias + l * ND, gamma + l * ND, beta + l * ND,
            out, h_nxt, l > 0, l == NL - 1);
        unsigned* t = h_cur; h_cur = h_nxt; h_nxt = t;
    }
}

// Round 10
// 733.296 us; speedup vs baseline: 2.1010x; 1.7565x over previous
//
#include <hip/hip_runtime.h>

#define NN 50000
#define NE 1600000
#define NR 8
#define ND 128
#define NL 3
#define RN (NR * NN)
#define SCAN_BLK 1024
#define NB ((RN + SCAN_BLK - 1) / SCAN_BLK)  // 391
#define LN_EPS 1e-5f
#define PADB 136   // bf16 elems per wave-tile row (272 B row stride)
#define PADB2 68   // dwords per wave-tile row
#define PADF 132   // f32 elems per epilogue scratch row (8448 B per wave region)

typedef __attribute__((ext_vector_type(8))) short short8;
typedef __attribute__((ext_vector_type(4))) float float4v;

__device__ __forceinline__ float bflo(unsigned u) { return __uint_as_float(u << 16); }
__device__ __forceinline__ float bfhi(unsigned u) { return __uint_as_float(u & 0xFFFF0000u); }
__device__ __forceinline__ unsigned f2bf(float f) {
    unsigned u = __float_as_uint(f);
    return (u + 0x7FFFu + ((u >> 16) & 1u)) >> 16;   // RNE
}
__device__ __forceinline__ unsigned pack2(float lo, float hi) {
    return f2bf(lo) | (f2bf(hi) << 16);
}

// h (row-major bf16x2): h[n*64+dw] = emb[x[n]] cols 2dw,2dw+1
__global__ __launch_bounds__(256) void k_gather(const int* __restrict__ x,
                                                const float* __restrict__ emb,
                                                unsigned* __restrict__ h) {
    int i = blockIdx.x * 256 + threadIdx.x;
    if (i >= NN * 64) return;
    int n = i >> 6, dw = i & 63;
    float2 v = *(const float2*)&emb[(size_t)x[n] * ND + 2 * dw];
    h[i] = pack2(v.x, v.y);
}

// weights -> bf16 B-fragment layout: wb[m][((kk*8+ft)*64+lane)*8+j] = W_m[kk*32+(lane>>4)*8+j][ft*16+(lane&15)]
__global__ __launch_bounds__(256) void k_wprep(const float* __restrict__ w_rel,
                                               const float* __restrict__ w_root,
                                               unsigned short* __restrict__ wb) {
    int i = blockIdx.x * 256 + threadIdx.x;
    if (i >= 27 * 16384) return;
    int m = i >> 14;
    int idx = i & 16383;
    int j = idx & 7;
    int lane = (idx >> 3) & 63;
    int ft = (idx >> 9) & 7;
    int kk = idx >> 12;
    int row = kk * 32 + (lane >> 4) * 8 + j;
    int col = ft * 16 + (lane & 15);
    const float* W = (m < 24) ? (w_rel + (size_t)m * 16384)
                              : (w_root + (size_t)(m - 24) * 16384);
    wb[i] = (unsigned short)f2bf(W[row * ND + col]);
}

__global__ __launch_bounds__(256) void k_count(const int* __restrict__ dst,
                                               const int* __restrict__ et,
                                               int* __restrict__ cnt) {
    int e = blockIdx.x * 256 + threadIdx.x;
    if (e >= NE) return;
    atomicAdd(&cnt[et[e] * NN + dst[e]], 1);
}

// scan over cnt -> rowstart (exclusive); also emits inv = 1/max(cnt,1)
__global__ __launch_bounds__(256) void k_scan1(const int* __restrict__ cnt,
                                               int* __restrict__ rowstart,
                                               int* __restrict__ bsum,
                                               float* __restrict__ inv) {
    __shared__ int tmp[256];
    int t = threadIdx.x;
    int base = blockIdx.x * SCAN_BLK + t * 4;
    int v[4];
#pragma unroll
    for (int i = 0; i < 4; i++) v[i] = (base + i < RN) ? cnt[base + i] : 0;
    int local = v[0] + v[1] + v[2] + v[3];
    tmp[t] = local;
    __syncthreads();
    for (int off = 1; off < 256; off <<= 1) {
        int x = (t >= off) ? tmp[t - off] : 0;
        __syncthreads();
        tmp[t] += x;
        __syncthreads();
    }
    int run = tmp[t] - local;
    if (t == 255) bsum[blockIdx.x] = tmp[t];
#pragma unroll
    for (int i = 0; i < 4; i++) {
        if (base + i < RN) {
            rowstart[base + i] = run;
            inv[base + i] = 1.0f / (float)(v[i] > 1 ? v[i] : 1);
        }
        run += v[i];
    }
}

__global__ __launch_bounds__(256) void k_scan2(const int* __restrict__ bsum,
                                               int* __restrict__ boff) {
    __shared__ int tmp[256];
    int t = threadIdx.x;
    int v0 = (2 * t < NB) ? bsum[2 * t] : 0;
    int v1 = (2 * t + 1 < NB) ? bsum[2 * t + 1] : 0;
    int local = v0 + v1;
    tmp[t] = local;
    __syncthreads();
    for (int off = 1; off < 256; off <<= 1) {
        int x = (t >= off) ? tmp[t - off] : 0;
        __syncthreads();
        tmp[t] += x;
        __syncthreads();
    }
    int excl = tmp[t] - local;
    if (2 * t < NB) boff[2 * t] = excl;
    if (2 * t + 1 < NB) boff[2 * t + 1] = excl + v0;
}

__global__ __launch_bounds__(256) void k_scan3(int* __restrict__ rowstart,
                                               const int* __restrict__ boff) {
    int i = blockIdx.x * 256 + threadIdx.x;
    if (i < RN) rowstart[i] += boff[i >> 10];
    if (i == 0) rowstart[RN] = NE;
}

__global__ __launch_bounds__(256) void k_fill(const int* __restrict__ src,
                                              const int* __restrict__ dst,
                                              const int* __restrict__ et,
                                              const int* __restrict__ rowstart,
                                              int* __restrict__ cnt,
                                              int* __restrict__ adj) {
    int e = blockIdx.x * 256 + threadIdx.x;
    if (e >= NE) return;
    int seg = et[e] * NN + dst[e];
    int c = atomicSub(&cnt[seg], 1);
    adj[rowstart[seg] + c - 1] = src[e];
}

// Fused RGCN layer, WAVE-AUTONOMOUS: block = 64 nodes, 4 waves; each wave owns
// its 16-row m-tile and a private LDS region. Gather->MFMA per relation with NO
// __syncthreads anywhere (within-wave LDS RAW ordered by lgkmcnt). Root
// transform + LN epilogue also wave-private. Slow CSR rows delay only their
// own wave; resident waves never park at barriers.
__global__ __launch_bounds__(256) void k_layer(const unsigned* __restrict__ h32,
                                               const int* __restrict__ adj,
                                               const int* __restrict__ rowstart,
                                               const float* __restrict__ inv,
                                               const unsigned short* __restrict__ wrel,
                                               const unsigned short* __restrict__ wroot,
                                               const float* __restrict__ bias,
                                               const float* __restrict__ gamma,
                                               const float* __restrict__ beta,
                                               float* __restrict__ out_f,
                                               unsigned* __restrict__ out_h,
                                               int add_res, int last) {
    __shared__ float SLF[4][16 * PADF];              // per-wave 8448 B regions, 33792 B total

    int tid = threadIdx.x;
    int wave = tid >> 6, lane = tid & 63;
    int quad = lane >> 4, l15 = lane & 15;
    int n0 = blockIdx.x * 64;
    int w0 = n0 + wave * 16;                         // wave's first global row

    float* WF = SLF[wave];                           // fp32 [16][PADF] epilogue view
    unsigned short* WB16 = (unsigned short*)WF;      // bf16 [16][PADB] tile view
    unsigned* WB32 = (unsigned*)WF;                  // dword [16][PADB2] tile view

    float4v acc[8];
#pragma unroll
    for (int i = 0; i < 8; i++) acc[i] = (float4v){0.f, 0.f, 0.f, 0.f};

    for (int r = 0; r < NR; r++) {
        // gather+mean into the wave's own tile: 4 batches of 4 quad-chains
        for (int b = 0; b < 4; b++) {
            int row = b * 4 + quad;                  // 0..15 within wave tile
            int g = w0 + row;
            float a0 = 0.f, a1 = 0.f, a2 = 0.f, a3 = 0.f,
                  a4 = 0.f, a5 = 0.f, a6 = 0.f, a7 = 0.f;
            if (g < NN) {
                int seg = r * NN + g;
                int st = rowstart[seg], en = rowstart[seg + 1];
                st = st < 0 ? 0 : st;
                en = en > NE ? NE : en;
                float c0 = 0.f, c1 = 0.f, c2 = 0.f, c3 = 0.f,
                      c4 = 0.f, c5 = 0.f, c6 = 0.f, c7 = 0.f;
                int p = st;
                for (; p + 1 < en; p += 2) {
                    unsigned s0 = (unsigned)adj[p], s1 = (unsigned)adj[p + 1];
                    s0 = s0 < NN ? s0 : NN - 1;
                    s1 = s1 < NN ? s1 : NN - 1;
                    uint4 u0 = *(const uint4*)&h32[(size_t)s0 * 64 + l15 * 4];
                    uint4 u1 = *(const uint4*)&h32[(size_t)s1 * 64 + l15 * 4];
                    a0 += bflo(u0.x); a1 += bfhi(u0.x);
                    a2 += bflo(u0.y); a3 += bfhi(u0.y);
                    a4 += bflo(u0.z); a5 += bfhi(u0.z);
                    a6 += bflo(u0.w); a7 += bfhi(u0.w);
                    c0 += bflo(u1.x); c1 += bfhi(u1.x);
                    c2 += bflo(u1.y); c3 += bfhi(u1.y);
                    c4 += bflo(u1.z); c5 += bfhi(u1.z);
                    c6 += bflo(u1.w); c7 += bfhi(u1.w);
                }
                if (p < en) {
                    unsigned s0 = (unsigned)adj[p];
                    s0 = s0 < NN ? s0 : NN - 1;
                    uint4 u0 = *(const uint4*)&h32[(size_t)s0 * 64 + l15 * 4];
                    a0 += bflo(u0.x); a1 += bfhi(u0.x);
                    a2 += bflo(u0.y); a3 += bfhi(u0.y);
                    a4 += bflo(u0.z); a5 += bfhi(u0.z);
                    a6 += bflo(u0.w); a7 += bfhi(u0.w);
                }
                float sc = inv[seg];
                a0 = (a0 + c0) * sc; a1 = (a1 + c1) * sc;
                a2 = (a2 + c2) * sc; a3 = (a3 + c3) * sc;
                a4 = (a4 + c4) * sc; a5 = (a5 + c5) * sc;
                a6 = (a6 + c6) * sc; a7 = (a7 + c7) * sc;
            }
            uint4 w;
            w.x = pack2(a0, a1); w.y = pack2(a2, a3);
            w.z = pack2(a4, a5); w.w = pack2(a6, a7);
            *(uint4*)&WB32[row * PADB2 + l15 * 4] = w;
        }
        // no barrier: wave reads its own tile (lgkmcnt orders LDS RAW)
        const unsigned short* WB = wrel + r * 16384;
#pragma unroll
        for (int kk = 0; kk < 4; kk++) {
            short8 af = *(const short8*)&WB16[l15 * PADB + kk * 32 + quad * 8];
#pragma unroll
            for (int ft = 0; ft < 8; ft++) {
                short8 bf = *(const short8*)&WB[((kk * 8 + ft) * 64 + lane) * 8];
                acc[ft] = __builtin_amdgcn_mfma_f32_16x16x32_bf16(af, bf, acc[ft], 0, 0, 0);
            }
        }
    }

    // root transform: wave stages its own 16 h rows, then MFMA with wroot
#pragma unroll
    for (int b = 0; b < 4; b++) {
        int row = b * 4 + quad;
        int g = w0 + row;
        uint4 v = make_uint4(0u, 0u, 0u, 0u);
        if (g < NN) v = *(const uint4*)&h32[(size_t)g * 64 + l15 * 4];
        *(uint4*)&WB32[row * PADB2 + l15 * 4] = v;
    }
#pragma unroll
    for (int kk = 0; kk < 4; kk++) {
        short8 af = *(const short8*)&WB16[l15 * PADB + kk * 32 + quad * 8];
#pragma unroll
        for (int ft = 0; ft < 8; ft++) {
            short8 bf = *(const short8*)&wroot[((kk * 8 + ft) * 64 + lane) * 8];
            acc[ft] = __builtin_amdgcn_mfma_f32_16x16x32_bf16(af, bf, acc[ft], 0, 0, 0);
        }
    }

    // epilogue (wave-private): acc (C layout: row=quad*4+rg, col=ft*16+l15) -> fp32 LDS
#pragma unroll
    for (int ft = 0; ft < 8; ft++)
#pragma unroll
        for (int rg = 0; rg < 4; rg++)
            WF[(quad * 4 + rg) * PADF + ft * 16 + l15] = acc[ft][rg];

    float2 bia = *(const float2*)&bias[2 * lane];
    float2 gam = *(const float2*)&gamma[2 * lane];
    float2 bet = *(const float2*)&beta[2 * lane];

    for (int i = 0; i < 16; i++) {
        int g = w0 + i;
        if (g >= NN) continue;                       // wave-uniform
        float v0 = WF[i * PADF + 2 * lane] + bia.x;
        float v1 = WF[i * PADF + 2 * lane + 1] + bia.y;
        float s = v0 + v1;
#pragma unroll
        for (int off = 32; off > 0; off >>= 1) s += __shfl_xor(s, off, 64);
        float mu = s * (1.0f / ND);
        float e0 = v0 - mu, e1 = v1 - mu;
        float vs = e0 * e0 + e1 * e1;
#pragma unroll
        for (int off = 32; off > 0; off >>= 1) vs += __shfl_xor(vs, off, 64);
        float rr = rsqrtf(vs * (1.0f / ND) + LN_EPS);
        float o0 = fmaxf(e0 * rr * gam.x + bet.x, 0.0f);
        float o1 = fmaxf(e1 * rr * gam.y + bet.y, 0.0f);
        if (add_res) {
            unsigned u = h32[(size_t)g * 64 + lane];
            o0 += bflo(u);
            o1 += bfhi(u);
        }
        if (last) {
            *(float2*)&out_f[(size_t)g * ND + 2 * lane] = make_float2(o0, o1);
        } else {
            out_h[(size_t)g * 64 + lane] = pack2(o0, o1);
        }
    }
}

extern "C" void kernel_launch(void* const* d_in, const int* in_sizes, int n_in,
                              void* d_out, int out_size, void* d_ws, size_t ws_size,
                              hipStream_t stream) {
    const int*   x      = (const int*)d_in[0];
    const int*   ei     = (const int*)d_in[1];
    const int*   et     = (const int*)d_in[2];
    const float* emb    = (const float*)d_in[3];
    const float* w_rel  = (const float*)d_in[4];
    const float* w_root = (const float*)d_in[5];
    const float* bias   = (const float*)d_in[6];
    const float* gamma  = (const float*)d_in[7];
    const float* beta   = (const float*)d_in[8];
    float* out = (float*)d_out;

    char* ws = (char*)d_ws;
    unsigned* h_a      = (unsigned*)(ws);                    // 12.8 MB (bf16x2, row-major)
    unsigned* h_b      = (unsigned*)(ws + 12800000);         // 12.8 MB
    int*      cnt      = (int*)     (ws + 25600000);         // 1.6 MB
    float*    inv      = (float*)   (ws + 27200000);         // 1.6 MB
    int*      rowstart = (int*)     (ws + 28800000);         // 1.6 MB + 4
    int*      bsum     = (int*)     (ws + 30400064);
    int*      boff     = (int*)     (ws + 30402048);
    int*      adj      = (int*)     (ws + 30404096);         // 6.4 MB
    unsigned short* wb = (unsigned short*)(ws + 36804096);   // 884736 B

    const int* src = ei;
    const int* dst = ei + NE;

    hipMemsetAsync(cnt, 0, RN * sizeof(int), stream);
    k_gather<<<(NN * 64 + 255) / 256, 256, 0, stream>>>(x, emb, h_a);
    k_wprep<<<(27 * 16384 + 255) / 256, 256, 0, stream>>>(w_rel, w_root, wb);
    k_count<<<(NE + 255) / 256, 256, 0, stream>>>(dst, et, cnt);
    k_scan1<<<NB, 256, 0, stream>>>(cnt, rowstart, bsum, inv);
    k_scan2<<<1, 256, 0, stream>>>(bsum, boff);
    k_scan3<<<(RN + 255) / 256, 256, 0, stream>>>(rowstart, boff);
    k_fill<<<(NE + 255) / 256, 256, 0, stream>>>(src, dst, et, rowstart, cnt, adj);

    unsigned* h_cur = h_a;
    unsigned* h_nxt = h_b;
    for (int l = 0; l < NL; l++) {
        k_layer<<<(NN + 63) / 64, 256, 0, stream>>>(
            h_cur, adj, rowstart, inv,
            wb + (size_t)l * 8 * 16384, wb + (size_t)(24 + l) * 16384,
            bias + l * ND, gamma + l * ND, beta + l * ND,
            out, h_nxt, l > 0, l == NL - 1);
        unsigned* t = h_cur; h_cur = h_nxt; h_nxt = t;
    }
}